// Round 17
// baseline (82862.341 us; speedup 1.0000x reference)
//
#include <hip/hip_runtime.h>
#include <math.h>

#define BB 512   // batch
#define TT 256   // time steps
#define EE 128   // hidden
#define GG 512   // 4*E gate rows
#define XROW 257 // T+1
#define NCHUNK 5 // decoder chunks per id
#define LOG2E 1.44269504088896f

typedef __attribute__((ext_vector_type(8))) short bf16x8;
typedef __attribute__((ext_vector_type(4))) float f32x4;

__device__ __forceinline__ unsigned short bf16_(float f){  // RNE f32->bf16
    unsigned u = __float_as_uint(f);
    return (unsigned short)((u + 0x7fffu + ((u>>16)&1u)) >> 16);
}
__device__ __forceinline__ float sig_pre(float a){
    float e; asm("v_exp_f32 %0, -%1" : "=v"(e) : "v"(a));
    float r; asm("v_rcp_f32 %0, %1" : "=v"(r) : "v"(e + 1.0f));
    return r;
}
__device__ __forceinline__ float tanh_pre(float a){
    float a2 = a + a;
    float e; asm("v_exp_f32 %0, -%1" : "=v"(e) : "v"(a2));
    float r; asm("v_rcp_f32 %0, %1" : "=v"(r) : "v"(e + 1.0f));
    return fmaf(2.0f, r, -1.0f);
}
__device__ __forceinline__ float tanh_raw(float x){
    float m = x * (-2.0f * LOG2E);
    float e; asm("v_exp_f32 %0, %1" : "=v"(e) : "v"(m));
    float r; asm("v_rcp_f32 %0, %1" : "=v"(r) : "v"(e + 1.0f));
    return fmaf(2.0f, r, -1.0f);
}
__device__ __forceinline__ int perm_row16(int P, int w, int rho){
    return (rho & 3)*EE + 8*w + 2*(rho >> 2) + P;
}
__device__ __forceinline__ bf16x8 load_afrag(const float* W, int row, int k0){
    const float4* p = (const float4*)(W + row*EE + k0);
    float4 a = p[0], b = p[1];
    bf16x8 r;
    r[0]=(short)bf16_(a.x*LOG2E); r[1]=(short)bf16_(a.y*LOG2E);
    r[2]=(short)bf16_(a.z*LOG2E); r[3]=(short)bf16_(a.w*LOG2E);
    r[4]=(short)bf16_(b.x*LOG2E); r[5]=(short)bf16_(b.y*LOG2E);
    r[6]=(short)bf16_(b.z*LOG2E); r[7]=(short)bf16_(b.w*LOG2E);
    return r;
}

// ===========================================================================
// CANDIDATE 8-wave encoder: exports STEP-0 and STEP-1 h/c (bf16-packed) to
// the diagnostic scratch; writes NO finals (authoritative encoder overwrites
// all scratch at s=255). wsd u32 layout: [s*65536 + gb*64 + e/2] = packed h,
// [s*65536 + 32768 + gb*64 + e/2] = packed c, for s in {0,1}.
// ===========================================================================
__device__ __forceinline__ int perm_row8(int j, int w, int rho){
    return (rho & 3)*EE + 16*w + 8*(j >> 1) + 2*(rho >> 2) + (j & 1);
}

__global__ __attribute__((amdgpu_flat_work_group_size(512,512)))
void enc8(const float* __restrict__ x,
          const float* __restrict__ Wg,
          const float* __restrict__ wib,
          const float* __restrict__ bbb,
          unsigned* __restrict__ wsd)
{
    const int t    = threadIdx.x;   // 512 threads = 8 waves
    const int w    = t >> 6;
    const int lane = t & 63;
    const int q    = lane >> 4;
    const int c    = lane & 15;

    __shared__ unsigned short h_lds[2][16*EE];
    __shared__ float x_lds[TT*16];

    for (int j = t; j < TT*16; j += 512){
        int s = j >> 4, cc = j & 15;
        x_lds[j] = x[(blockIdx.x*16 + cc)*XROW + s];
    }

    const int kb = 8*q;
    const int r0 = perm_row8(0, w, c), r1 = perm_row8(1, w, c);
    const int r2 = perm_row8(2, w, c), r3 = perm_row8(3, w, c);
    bf16x8 a0_0 = load_afrag(Wg, r0, kb),    a0_1 = load_afrag(Wg, r0, 32+kb);
    bf16x8 a0_2 = load_afrag(Wg, r0, 64+kb), a0_3 = load_afrag(Wg, r0, 96+kb);
    bf16x8 a1_0 = load_afrag(Wg, r1, kb),    a1_1 = load_afrag(Wg, r1, 32+kb);
    bf16x8 a1_2 = load_afrag(Wg, r1, 64+kb), a1_3 = load_afrag(Wg, r1, 96+kb);
    bf16x8 a2_0 = load_afrag(Wg, r2, kb),    a2_1 = load_afrag(Wg, r2, 32+kb);
    bf16x8 a2_2 = load_afrag(Wg, r2, 64+kb), a2_3 = load_afrag(Wg, r2, 96+kb);
    bf16x8 a3_0 = load_afrag(Wg, r3, kb),    a3_1 = load_afrag(Wg, r3, 32+kb);
    bf16x8 a3_2 = load_afrag(Wg, r3, 64+kb), a3_3 = load_afrag(Wg, r3, 96+kb);
    bf16x8 k0 = {0,0,0,0,0,0,0,0}, k1 = {0,0,0,0,0,0,0,0};
    bf16x8 k2 = {0,0,0,0,0,0,0,0}, k3 = {0,0,0,0,0,0,0,0};
    if (q == 0){
        k0[0] = (short)bf16_(bbb[r0]*LOG2E); k0[1] = (short)bf16_(wib[r0]*LOG2E);
        k1[0] = (short)bf16_(bbb[r1]*LOG2E); k1[1] = (short)bf16_(wib[r1]*LOG2E);
        k2[0] = (short)bf16_(bbb[r2]*LOG2E); k2[1] = (short)bf16_(wib[r2]*LOG2E);
        k3[0] = (short)bf16_(bbb[r3]*LOG2E); k3[1] = (short)bf16_(wib[r3]*LOG2E);
    }

    float cst0 = 0.f, cst1 = 0.f, cst2 = 0.f, cst3 = 0.f;
    for (int j = t; j < 1024; j += 512) ((unsigned*)&h_lds[0][0])[j] = 0u;
    __syncthreads();

    for (int s = 0; s < TT; ++s){
        const int cur = s & 1;
        float u = x_lds[s*16 + c];
        unsigned pk;
        asm("v_cvt_pk_bf16_f32 %0, %1, %2" : "=v"(pk) : "v"(1.0f), "v"(u));
        union { bf16x8 v; unsigned uu[4]; } bu;
        bu.uu[0] = (q == 0) ? pk : 0u;
        bu.uu[1] = 0u; bu.uu[2] = 0u; bu.uu[3] = 0u;

        f32x4 acc0 = {0,0,0,0}, acc1 = {0,0,0,0}, acc2 = {0,0,0,0}, acc3 = {0,0,0,0};
        acc0 = __builtin_amdgcn_mfma_f32_16x16x32_bf16(k0, bu.v, acc0, 0,0,0);
        acc1 = __builtin_amdgcn_mfma_f32_16x16x32_bf16(k1, bu.v, acc1, 0,0,0);
        acc2 = __builtin_amdgcn_mfma_f32_16x16x32_bf16(k2, bu.v, acc2, 0,0,0);
        acc3 = __builtin_amdgcn_mfma_f32_16x16x32_bf16(k3, bu.v, acc3, 0,0,0);

        const unsigned short* hb = &h_lds[cur][c*EE];
        {
            bf16x8 bf = *(const bf16x8*)&hb[(((0 + q) ^ c) << 3)];
            acc0 = __builtin_amdgcn_mfma_f32_16x16x32_bf16(a0_0, bf, acc0, 0,0,0);
            acc1 = __builtin_amdgcn_mfma_f32_16x16x32_bf16(a1_0, bf, acc1, 0,0,0);
            acc2 = __builtin_amdgcn_mfma_f32_16x16x32_bf16(a2_0, bf, acc2, 0,0,0);
            acc3 = __builtin_amdgcn_mfma_f32_16x16x32_bf16(a3_0, bf, acc3, 0,0,0);
        }
        {
            bf16x8 bf = *(const bf16x8*)&hb[(((4 + q) ^ c) << 3)];
            acc0 = __builtin_amdgcn_mfma_f32_16x16x32_bf16(a0_1, bf, acc0, 0,0,0);
            acc1 = __builtin_amdgcn_mfma_f32_16x16x32_bf16(a1_1, bf, acc1, 0,0,0);
            acc2 = __builtin_amdgcn_mfma_f32_16x16x32_bf16(a2_1, bf, acc2, 0,0,0);
            acc3 = __builtin_amdgcn_mfma_f32_16x16x32_bf16(a3_1, bf, acc3, 0,0,0);
        }
        {
            bf16x8 bf = *(const bf16x8*)&hb[(((8 + q) ^ c) << 3)];
            acc0 = __builtin_amdgcn_mfma_f32_16x16x32_bf16(a0_2, bf, acc0, 0,0,0);
            acc1 = __builtin_amdgcn_mfma_f32_16x16x32_bf16(a1_2, bf, acc1, 0,0,0);
            acc2 = __builtin_amdgcn_mfma_f32_16x16x32_bf16(a2_2, bf, acc2, 0,0,0);
            acc3 = __builtin_amdgcn_mfma_f32_16x16x32_bf16(a3_2, bf, acc3, 0,0,0);
        }
        {
            bf16x8 bf = *(const bf16x8*)&hb[(((12 + q) ^ c) << 3)];
            acc0 = __builtin_amdgcn_mfma_f32_16x16x32_bf16(a0_3, bf, acc0, 0,0,0);
            acc1 = __builtin_amdgcn_mfma_f32_16x16x32_bf16(a1_3, bf, acc1, 0,0,0);
            acc2 = __builtin_amdgcn_mfma_f32_16x16x32_bf16(a2_3, bf, acc2, 0,0,0);
            acc3 = __builtin_amdgcn_mfma_f32_16x16x32_bf16(a3_3, bf, acc3, 0,0,0);
        }

        float h0, h1, h2, h3;
        {
            float i_ = sig_pre(acc0[0]), f_ = sig_pre(acc0[1]);
            float g_ = tanh_pre(acc0[2]), o_ = sig_pre(acc0[3]);
            cst0 = fmaf(f_, cst0, i_*g_); h0 = o_ * tanh_raw(cst0);
        }
        {
            float i_ = sig_pre(acc1[0]), f_ = sig_pre(acc1[1]);
            float g_ = tanh_pre(acc1[2]), o_ = sig_pre(acc1[3]);
            cst1 = fmaf(f_, cst1, i_*g_); h1 = o_ * tanh_raw(cst1);
        }
        {
            float i_ = sig_pre(acc2[0]), f_ = sig_pre(acc2[1]);
            float g_ = tanh_pre(acc2[2]), o_ = sig_pre(acc2[3]);
            cst2 = fmaf(f_, cst2, i_*g_); h2 = o_ * tanh_raw(cst2);
        }
        {
            float i_ = sig_pre(acc3[0]), f_ = sig_pre(acc3[1]);
            float g_ = tanh_pre(acc3[2]), o_ = sig_pre(acc3[3]);
            cst3 = fmaf(f_, cst3, i_*g_); h3 = o_ * tanh_raw(cst3);
        }

        unsigned hpA, hpB;
        asm("v_cvt_pk_bf16_f32 %0, %1, %2" : "=v"(hpA) : "v"(h0), "v"(h1));
        asm("v_cvt_pk_bf16_f32 %0, %1, %2" : "=v"(hpB) : "v"(h2), "v"(h3));
        *(unsigned*)&h_lds[cur ^ 1][c*EE + (((2*w) ^ c) << 3) + 2*q] = hpA;
        *(unsigned*)&h_lds[cur ^ 1][c*EE + (((2*w + 1) ^ c) << 3) + 2*q] = hpB;

        if (s < 2){   // export step-0 / step-1 state for the oracle
            unsigned cpA, cpB;
            asm("v_cvt_pk_bf16_f32 %0, %1, %2" : "=v"(cpA) : "v"(cst0), "v"(cst1));
            asm("v_cvt_pk_bf16_f32 %0, %1, %2" : "=v"(cpB) : "v"(cst2), "v"(cst3));
            int gb = blockIdx.x*16 + c;
            unsigned base = (unsigned)s * 65536u;
            wsd[base + gb*64 + 8*w + q]             = hpA;   // e/2 = 8w+q
            wsd[base + gb*64 + 8*w + 4 + q]         = hpB;   // e/2 = 8w+4+q
            wsd[base + 32768u + gb*64 + 8*w + q]     = cpA;
            wsd[base + 32768u + gb*64 + 8*w + 4 + q] = cpB;
        }
        __syncthreads();
    }
}

// ===========================================================================
// PROVEN r13 kernel (16 waves). Encoder instantiation bit-compares enc8's
// step-0/step-1 exports and spins with DISTINCT durations on mismatch
// (s0: 1M iters ~+3.7ms; s1: 3M ~+11ms). Finals overwrite all scratch.
// ===========================================================================
template <int IS_DEC>
__global__ __attribute__((amdgpu_flat_work_group_size(1024,1024)))
void lstm_k(const float* __restrict__ x,
            const float* __restrict__ Wg_all,
            const float* __restrict__ wi_all,
            const float* __restrict__ b_all,
            const float* __restrict__ lw_all,
            const float* __restrict__ lb_all,
            float* __restrict__ ws_h,
            float* __restrict__ ws_c,
            unsigned* __restrict__ wsd,
            float* __restrict__ out)
{
    const int t    = threadIdx.x;   // 1024 threads = 16 waves
    const int w    = t >> 6;
    const int lane = t & 63;
    const int q    = lane >> 4;
    const int c    = lane & 15;

    __shared__ unsigned short h_lds[2][16*EE];
    __shared__ float x_lds[TT*16];
    __shared__ float psum_lds[2][512];
    __shared__ float u0_lds[16];
    __shared__ float out_lds[16][TT+1];
    __shared__ int   id_lds[BB];
    __shared__ int   blist[16];
    __shared__ int   nslots_s;
    __shared__ float bl_sh;

    int myid = 0, nslots = 16;
    if (IS_DEC){
        myid = blockIdx.x / NCHUNK;
        int chunk = blockIdx.x % NCHUNK;
        for (int j = t; j < BB; j += 1024) id_lds[j] = (int)x[j*XROW + TT];
        if (t < 16) blist[t] = 0;
        __syncthreads();
        if (t < BB && id_lds[t] == myid){
            int r = 0;
            for (int j = 0; j < t; ++j) r += (id_lds[j] == myid) ? 1 : 0;
            int slot = r - chunk*16;
            if (slot >= 0 && slot < 16) blist[slot] = t;
        }
        if (t == 0){
            int cnt = 0;
            for (int j = 0; j < BB; ++j) cnt += (id_lds[j] == myid) ? 1 : 0;
            int ns = cnt - chunk*16;
            nslots_s = ns < 0 ? 0 : (ns > 16 ? 16 : ns);
            bl_sh = lb_all[myid];
        }
        __syncthreads();
        nslots = nslots_s;
        if (nslots == 0) return;
    }
    const int gb = IS_DEC ? blist[c] : (blockIdx.x*16 + c);

    for (int j = t; j < TT*16; j += 1024){
        int s = j >> 4, cc = j & 15;
        int gbl = IS_DEC ? blist[cc] : (blockIdx.x*16 + cc);
        x_lds[j] = x[gbl*XROW + s];
    }

    const float* Wb  = Wg_all + (IS_DEC ? myid*GG*EE : 0);
    const float* wib = wi_all + (IS_DEC ? myid*GG : 0);
    const float* bbb = b_all  + (IS_DEC ? myid*GG : 0);

    bf16x8 a00, a01, a02, a03, a10, a11, a12, a13;
    bf16x8 a40 = {0,0,0,0,0,0,0,0}, a41 = {0,0,0,0,0,0,0,0};
    {
        int kb = 8*q;
        int r0 = perm_row16(0, w, c), r1 = perm_row16(1, w, c);
        a00 = load_afrag(Wb, r0, kb);      a10 = load_afrag(Wb, r1, kb);
        a01 = load_afrag(Wb, r0, 32+kb);   a11 = load_afrag(Wb, r1, 32+kb);
        a02 = load_afrag(Wb, r0, 64+kb);   a12 = load_afrag(Wb, r1, 64+kb);
        a03 = load_afrag(Wb, r0, 96+kb);   a13 = load_afrag(Wb, r1, 96+kb);
        if (q == 0){
            a40[0] = (short)bf16_(bbb[r0]*LOG2E); a40[1] = (short)bf16_(wib[r0]*LOG2E);
            a41[0] = (short)bf16_(bbb[r1]*LOG2E); a41[1] = (short)bf16_(wib[r1]*LOG2E);
        }
    }

    const int e0 = 8*w + 2*q;
    float cst0 = 0.f, cst1 = 0.f;
    float wl0 = 0.f, wl1 = 0.f;

    if (!IS_DEC){
        ((unsigned*)&h_lds[0][0])[t] = 0u;
    } else {
        float2 hv = *(const float2*)&ws_h[gb*EE + e0];
        float2 cv = *(const float2*)&ws_c[gb*EE + e0];
        cst0 = cv.x; cst1 = cv.y;
        float2 wv = *(const float2*)&lw_all[myid*EE + e0];
        wl0 = wv.x; wl1 = wv.y;
        unsigned hp;
        asm("v_cvt_pk_bf16_f32 %0, %1, %2" : "=v"(hp) : "v"(hv.x), "v"(hv.y));
        *(unsigned*)&h_lds[0][c*EE + ((w ^ c) << 3) + 2*q] = hp;
        float p = hv.x*wl0 + hv.y*wl1;
        p += __shfl_xor(p, 16);
        if ((q & 1) == 0) psum_lds[0][(2*w + (q >> 1))*16 + c] = p;
    }
    __syncthreads();
    if (IS_DEC && t < 16){
        float s32 = 0.f;
        #pragma unroll
        for (int j = 0; j < 32; ++j) s32 += psum_lds[0][j*16 + t];
        u0_lds[t] = s32 + bl_sh;
    }
    __syncthreads();

    for (int s = 0; s < TT; ++s){
        const int cur = s & 1;
        if (IS_DEC && s > 0 && w == (s & 15) && lane < 16){
            float s32 = 0.f;
            #pragma unroll
            for (int j = 0; j < 32; ++j) s32 += psum_lds[cur ^ 1][j*16 + lane];
            out_lds[lane][TT - s] = s32 + bl_sh;
        }

        float u;
        if (IS_DEC) u = (s == 0) ? u0_lds[c] : x_lds[(TT - s)*16 + c];
        else        u = x_lds[s*16 + c];

        unsigned pk;
        asm("v_cvt_pk_bf16_f32 %0, %1, %2" : "=v"(pk) : "v"(1.0f), "v"(u));
        union { bf16x8 v; unsigned uu[4]; } bu;
        bu.uu[0] = (q == 0) ? pk : 0u;
        bu.uu[1] = 0u; bu.uu[2] = 0u; bu.uu[3] = 0u;

        f32x4 acc0 = {0,0,0,0}, acc1 = {0,0,0,0};
        acc0 = __builtin_amdgcn_mfma_f32_16x16x32_bf16(a40, bu.v, acc0, 0,0,0);
        acc1 = __builtin_amdgcn_mfma_f32_16x16x32_bf16(a41, bu.v, acc1, 0,0,0);

        const unsigned short* hb = &h_lds[cur][c*EE];
        {
            bf16x8 bf0 = *(const bf16x8*)&hb[(((0 + q) ^ c) << 3)];
            acc0 = __builtin_amdgcn_mfma_f32_16x16x32_bf16(a00, bf0, acc0, 0,0,0);
            acc1 = __builtin_amdgcn_mfma_f32_16x16x32_bf16(a10, bf0, acc1, 0,0,0);
            bf16x8 bf1 = *(const bf16x8*)&hb[(((4 + q) ^ c) << 3)];
            acc0 = __builtin_amdgcn_mfma_f32_16x16x32_bf16(a01, bf1, acc0, 0,0,0);
            acc1 = __builtin_amdgcn_mfma_f32_16x16x32_bf16(a11, bf1, acc1, 0,0,0);
            bf16x8 bf2 = *(const bf16x8*)&hb[(((8 + q) ^ c) << 3)];
            acc0 = __builtin_amdgcn_mfma_f32_16x16x32_bf16(a02, bf2, acc0, 0,0,0);
            acc1 = __builtin_amdgcn_mfma_f32_16x16x32_bf16(a12, bf2, acc1, 0,0,0);
            bf16x8 bf3 = *(const bf16x8*)&hb[(((12 + q) ^ c) << 3)];
            acc0 = __builtin_amdgcn_mfma_f32_16x16x32_bf16(a03, bf3, acc0, 0,0,0);
            acc1 = __builtin_amdgcn_mfma_f32_16x16x32_bf16(a13, bf3, acc1, 0,0,0);
        }

        float i0 = sig_pre (acc0[0]);
        float f0 = sig_pre (acc0[1]);
        float g0 = tanh_pre(acc0[2]);
        float o0 = sig_pre (acc0[3]);
        cst0 = fmaf(f0, cst0, i0*g0);
        float h0 = o0 * tanh_raw(cst0);
        float i1 = sig_pre (acc1[0]);
        float f1 = sig_pre (acc1[1]);
        float g1 = tanh_pre(acc1[2]);
        float o1 = sig_pre (acc1[3]);
        cst1 = fmaf(f1, cst1, i1*g1);
        float h1 = o1 * tanh_raw(cst1);

        unsigned hp;
        asm("v_cvt_pk_bf16_f32 %0, %1, %2" : "=v"(hp) : "v"(h0), "v"(h1));
        *(unsigned*)&h_lds[cur ^ 1][c*EE + ((w ^ c) << 3) + 2*q] = hp;

        if (IS_DEC){
            float p = h0*wl0 + h1*wl1;
            p += __shfl_xor(p, 16);
            if ((q & 1) == 0) psum_lds[cur][(2*w + (q >> 1))*16 + c] = p;
        }
        if (!IS_DEC && s < 2){
            // ---- localizing oracle: bit-compare enc8's step-s export
            unsigned cp;
            asm("v_cvt_pk_bf16_f32 %0, %1, %2" : "=v"(cp) : "v"(cst0), "v"(cst1));
            unsigned base = (unsigned)s * 65536u;
            unsigned idx = gb*64 + 4*w + q;   // e0/2
            bool bad = (wsd[base + idx] != hp) | (wsd[base + 32768u + idx] != cp);
            if (__ballot(bad) != 0ULL){
                int iters = (s == 0) ? 1000000 : 3000000;
                float spin = 1.0f + (float)lane;
                for (int i = 0; i < iters; ++i){
                    spin = fmaf(spin, 1.0000001f, 1.0e-9f);
                    asm volatile("" : "+v"(spin));
                }
                if (spin > 1.0e30f) out[0] = spin;  // never true; keeps spin live
            }
        }
        if (!IS_DEC && s == TT-1){
            *(float2*)&ws_h[gb*EE + e0] = make_float2(h0, h1);
            *(float2*)&ws_c[gb*EE + e0] = make_float2(cst0, cst1);
        }
        __syncthreads();
    }

    if (IS_DEC){
        if (w == 0 && lane < 16){
            float s32 = 0.f;
            #pragma unroll
            for (int j = 0; j < 32; ++j) s32 += psum_lds[(TT-1)&1][j*16 + lane];
            out_lds[lane][0] = s32 + bl_sh;
        }
        __syncthreads();
        for (int j = t; j < 16*TT; j += 1024){
            int sl = j >> 8, pos = j & 255;
            if (sl < nslots) out[blist[sl]*TT + pos] = out_lds[sl][pos];
        }
    }
}

extern "C" void kernel_launch(void* const* d_in, const int* in_sizes, int n_in,
                              void* d_out, int out_size, void* d_ws, size_t ws_size,
                              hipStream_t stream) {
    const float* x       = (const float*)d_in[0];
    const float* enc_wih = (const float*)d_in[1];
    const float* enc_whh = (const float*)d_in[2];
    const float* enc_b   = (const float*)d_in[3];
    const float* dec_wih = (const float*)d_in[4];
    const float* dec_whh = (const float*)d_in[5];
    const float* dec_b   = (const float*)d_in[6];
    const float* lin_w   = (const float*)d_in[7];
    const float* lin_b   = (const float*)d_in[8];
    float* out  = (float*)d_out;
    float* wsf  = (float*)d_ws;
    float* ws_h = wsf;
    float* ws_c = wsf + BB*EE;        // same 512 KB footprint as r13
    unsigned* wsd = (unsigned*)d_ws;  // diagnostic aliases the same scratch

    // candidate: exports step-0/1 state into wsd (no finals)
    hipLaunchKernelGGL(enc8, dim3(BB/16), dim3(512), 0, stream,
                       x, enc_whh, enc_wih, enc_b, wsd);
    // authoritative encoder (+localizing oracle) and decoder (r13, proven)
    hipLaunchKernelGGL((lstm_k<0>), dim3(BB/16), dim3(1024), 0, stream,
                       x, enc_whh, enc_wih, enc_b, lin_w, lin_b, ws_h, ws_c, wsd, out);
    hipLaunchKernelGGL((lstm_k<1>), dim3(16*NCHUNK), dim3(1024), 0, stream,
                       x, dec_whh, dec_wih, dec_b, lin_w, lin_b, ws_h, ws_c, wsd, out);
}

// Round 19
// 456.901 us; speedup vs baseline: 181.3573x; 181.3573x over previous
//
#include <hip/hip_runtime.h>
#include <math.h>

#define BB 512   // batch
#define TT 256   // time steps
#define EE 128   // hidden
#define GG 512   // 4*E gate rows
#define XROW 257 // T+1
#define NCHUNK 5 // decoder chunks per id
#define LOG2E 1.44269504088896f

typedef __attribute__((ext_vector_type(8))) short bf16x8;
typedef __attribute__((ext_vector_type(4))) float f32x4;

__device__ __forceinline__ unsigned short bf16_(float f){  // RNE f32->bf16
    unsigned u = __float_as_uint(f);
    return (unsigned short)((u + 0x7fffu + ((u>>16)&1u)) >> 16);
}

// Nonlinearities on PRE-SCALED inputs (a = x*log2e): 2 TRANS + ~2 VALU each.
__device__ __forceinline__ float sig_pre(float a){   // sigmoid(x)
    float e; asm("v_exp_f32 %0, -%1" : "=v"(e) : "v"(a));
    float r; asm("v_rcp_f32 %0, %1" : "=v"(r) : "v"(e + 1.0f));
    return r;
}
__device__ __forceinline__ float tanh_pre(float a){  // tanh(x)
    float a2 = a + a;
    float e; asm("v_exp_f32 %0, -%1" : "=v"(e) : "v"(a2));
    float r; asm("v_rcp_f32 %0, %1" : "=v"(r) : "v"(e + 1.0f));
    return fmaf(2.0f, r, -1.0f);
}
__device__ __forceinline__ float tanh_raw(float x){  // unscaled input
    float m = x * (-2.0f * LOG2E);
    float e; asm("v_exp_f32 %0, %1" : "=v"(e) : "v"(m));
    float r; asm("v_rcp_f32 %0, %1" : "=v"(r) : "v"(e + 1.0f));
    return fmaf(2.0f, r, -1.0f);
}

// Adjacent-element gate-interleaved permutation: tile P of wave w, tile-row
// rho in [0,16): source gate row = (rho&3)*128 + 8w + 2*(rho>>2) + P.
// => C/D lane (q,c): acc_P regs 0..3 = gates (i,f,g,o) of element 8w+2q+P.
__device__ __forceinline__ int perm_row(int P, int w, int rho){
    return (rho & 3)*EE + 8*w + 2*(rho >> 2) + P;
}
// A-frag load with pre-scale (weights multiplied by log2e before bf16 round)
__device__ __forceinline__ bf16x8 load_afrag(const float* W, int row, int k0){
    const float4* p = (const float4*)(W + row*EE + k0);
    float4 a = p[0], b = p[1];
    bf16x8 r;
    r[0]=(short)bf16_(a.x*LOG2E); r[1]=(short)bf16_(a.y*LOG2E);
    r[2]=(short)bf16_(a.z*LOG2E); r[3]=(short)bf16_(a.w*LOG2E);
    r[4]=(short)bf16_(b.x*LOG2E); r[5]=(short)bf16_(b.y*LOG2E);
    r[6]=(short)bf16_(b.z*LOG2E); r[7]=(short)bf16_(b.w*LOG2E);
    return r;
}

template <int IS_DEC>
__global__ __attribute__((amdgpu_flat_work_group_size(1024,1024)))
void lstm_k(const float* __restrict__ x,
            const float* __restrict__ Wg_all,
            const float* __restrict__ wi_all,
            const float* __restrict__ b_all,
            const float* __restrict__ lw_all,
            const float* __restrict__ lb_all,
            float* __restrict__ ws_h,
            float* __restrict__ ws_c,
            float* __restrict__ out)
{
    const int t    = threadIdx.x;   // 1024 threads = 16 waves
    const int w    = t >> 6;        // wave owns e-chunk 8w..8w+7
    const int lane = t & 63;
    const int q    = lane >> 4;
    const int c    = lane & 15;     // batch column (B-frag) / tile-row (A-frag)

    __shared__ unsigned short h_lds[2][16*EE];  // double-buffered bf16 h, swizzled
    __shared__ float x_lds[TT*16];              // inputs [step][col]
    __shared__ float psum_lds[2][512];          // [buf][(2w+qh)*16+c]
    __shared__ float u0_lds[16];
    __shared__ float out_lds[16][TT+1];
    __shared__ int   id_lds[BB];
    __shared__ int   blist[16];
    __shared__ int   nslots_s;
    __shared__ float bl_sh;

    int myid = 0, nslots = 16;
    if (IS_DEC){
        myid = blockIdx.x / NCHUNK;
        int chunk = blockIdx.x % NCHUNK;
        for (int j = t; j < BB; j += 1024) id_lds[j] = (int)x[j*XROW + TT];
        if (t < 16) blist[t] = 0;
        __syncthreads();
        if (t < BB && id_lds[t] == myid){
            int r = 0;
            for (int j = 0; j < t; ++j) r += (id_lds[j] == myid) ? 1 : 0;
            int slot = r - chunk*16;
            if (slot >= 0 && slot < 16) blist[slot] = t;
        }
        if (t == 0){
            int cnt = 0;
            for (int j = 0; j < BB; ++j) cnt += (id_lds[j] == myid) ? 1 : 0;
            int ns = cnt - chunk*16;
            nslots_s = ns < 0 ? 0 : (ns > 16 ? 16 : ns);
            bl_sh = lb_all[myid];
        }
        __syncthreads();
        nslots = nslots_s;
        if (nslots == 0) return;    // uniform exit before loop barriers
    }
    const int gb = IS_DEC ? blist[c] : (blockIdx.x*16 + c);

    for (int j = t; j < TT*16; j += 1024){
        int s = j >> 4, cc = j & 15;
        int gbl = IS_DEC ? blist[cc] : (blockIdx.x*16 + cc);
        x_lds[j] = x[gbl*XROW + s];
    }

    const float* Wb  = Wg_all + (IS_DEC ? myid*GG*EE : 0);
    const float* wib = wi_all + (IS_DEC ? myid*GG : 0);
    const float* bbb = b_all  + (IS_DEC ? myid*GG : 0);

    // weights: 8 main A-frags (32 VGPR) + 2 K-ext frags (8 VGPR), pre-scaled
    bf16x8 a00, a01, a02, a03, a10, a11, a12, a13;
    bf16x8 a40 = {0,0,0,0,0,0,0,0}, a41 = {0,0,0,0,0,0,0,0};
    {
        int kb = 8*q;
        int r0 = perm_row(0, w, c), r1 = perm_row(1, w, c);
        a00 = load_afrag(Wb, r0, kb);      a10 = load_afrag(Wb, r1, kb);
        a01 = load_afrag(Wb, r0, 32+kb);   a11 = load_afrag(Wb, r1, 32+kb);
        a02 = load_afrag(Wb, r0, 64+kb);   a12 = load_afrag(Wb, r1, 64+kb);
        a03 = load_afrag(Wb, r0, 96+kb);   a13 = load_afrag(Wb, r1, 96+kb);
        if (q == 0){   // K-ext tile: k=0 -> bias, k=1 -> wi (both pre-scaled)
            a40[0] = (short)bf16_(bbb[r0]*LOG2E); a40[1] = (short)bf16_(wib[r0]*LOG2E);
            a41[0] = (short)bf16_(bbb[r1]*LOG2E); a41[1] = (short)bf16_(wib[r1]*LOG2E);
        }
    }

    const int e0 = 8*w + 2*q;       // lane's two adjacent elements e0, e0+1
    float cst0 = 0.f, cst1 = 0.f;
    float wl0 = 0.f, wl1 = 0.f;

    if (!IS_DEC){
        ((unsigned*)&h_lds[0][0])[t] = 0u;   // zero buf0
    } else {
        float2 hv = *(const float2*)&ws_h[gb*EE + e0];
        float2 cv = *(const float2*)&ws_c[gb*EE + e0];
        cst0 = cv.x; cst1 = cv.y;
        float2 wv = *(const float2*)&lw_all[myid*EE + e0];
        wl0 = wv.x; wl1 = wv.y;
        unsigned hp;
        asm("v_cvt_pk_bf16_f32 %0, %1, %2" : "=v"(hp) : "v"(hv.x), "v"(hv.y));
        *(unsigned*)&h_lds[0][c*EE + ((w ^ c) << 3) + 2*q] = hp;
        float p = hv.x*wl0 + hv.y*wl1;
        p += __shfl_xor(p, 16);      // q pairs (0,1) and (2,3) summed
        if ((q & 1) == 0) psum_lds[0][(2*w + (q >> 1))*16 + c] = p;
    }
    __syncthreads();
    if (IS_DEC && t < 16){
        float s32 = 0.f;
        #pragma unroll
        for (int j = 0; j < 32; ++j) s32 += psum_lds[0][j*16 + t];
        u0_lds[t] = s32 + bl_sh;
    }
    __syncthreads();

    for (int s = 0; s < TT; ++s){
        const int cur = s & 1;
        // rotated output flush of previous step (dec): one wave per step
        if (IS_DEC && s > 0 && w == (s & 15) && lane < 16){
            float s32 = 0.f;
            #pragma unroll
            for (int j = 0; j < 32; ++j) s32 += psum_lds[cur ^ 1][j*16 + lane];
            out_lds[lane][TT - s] = s32 + bl_sh;
        }

        float u;
        if (IS_DEC) u = (s == 0) ? u0_lds[c] : x_lds[(TT - s)*16 + c];
        else        u = x_lds[s*16 + c];

        // K-ext B-frag: col c, k=0 -> 1.0, k=1 -> u  (q==0 lanes only)
        unsigned pk;
        asm("v_cvt_pk_bf16_f32 %0, %1, %2" : "=v"(pk) : "v"(1.0f), "v"(u));
        union { bf16x8 v; unsigned uu[4]; } bu;
        bu.uu[0] = (q == 0) ? pk : 0u;
        bu.uu[1] = 0u; bu.uu[2] = 0u; bu.uu[3] = 0u;

        // K-ext MFMAs first: no LDS dependence, overlap the h ds_read latency
        f32x4 acc0 = {0,0,0,0}, acc1 = {0,0,0,0};
        acc0 = __builtin_amdgcn_mfma_f32_16x16x32_bf16(a40, bu.v, acc0, 0,0,0);
        acc1 = __builtin_amdgcn_mfma_f32_16x16x32_bf16(a41, bu.v, acc1, 0,0,0);

        const unsigned short* hb = &h_lds[cur][c*EE];
        {
            bf16x8 bf0 = *(const bf16x8*)&hb[(((0 + q) ^ c) << 3)];
            acc0 = __builtin_amdgcn_mfma_f32_16x16x32_bf16(a00, bf0, acc0, 0,0,0);
            acc1 = __builtin_amdgcn_mfma_f32_16x16x32_bf16(a10, bf0, acc1, 0,0,0);
            bf16x8 bf1 = *(const bf16x8*)&hb[(((4 + q) ^ c) << 3)];
            acc0 = __builtin_amdgcn_mfma_f32_16x16x32_bf16(a01, bf1, acc0, 0,0,0);
            acc1 = __builtin_amdgcn_mfma_f32_16x16x32_bf16(a11, bf1, acc1, 0,0,0);
            bf16x8 bf2 = *(const bf16x8*)&hb[(((8 + q) ^ c) << 3)];
            acc0 = __builtin_amdgcn_mfma_f32_16x16x32_bf16(a02, bf2, acc0, 0,0,0);
            acc1 = __builtin_amdgcn_mfma_f32_16x16x32_bf16(a12, bf2, acc1, 0,0,0);
            bf16x8 bf3 = *(const bf16x8*)&hb[(((12 + q) ^ c) << 3)];
            acc0 = __builtin_amdgcn_mfma_f32_16x16x32_bf16(a03, bf3, acc0, 0,0,0);
            acc1 = __builtin_amdgcn_mfma_f32_16x16x32_bf16(a13, bf3, acc1, 0,0,0);
        }

        // element e0: gates lane-local, acc pre-scaled by log2e
        float i0 = sig_pre (acc0[0]);
        float f0 = sig_pre (acc0[1]);
        float g0 = tanh_pre(acc0[2]);
        float o0 = sig_pre (acc0[3]);
        cst0 = fmaf(f0, cst0, i0*g0);
        float h0 = o0 * tanh_raw(cst0);
        // element e1
        float i1 = sig_pre (acc1[0]);
        float f1 = sig_pre (acc1[1]);
        float g1 = tanh_pre(acc1[2]);
        float o1 = sig_pre (acc1[3]);
        cst1 = fmaf(f1, cst1, i1*g1);
        float h1 = o1 * tanh_raw(cst1);

        // packed h write: one cvt_pk + one ds_write_b32 (2-way banks = free)
        unsigned hp;
        asm("v_cvt_pk_bf16_f32 %0, %1, %2" : "=v"(hp) : "v"(h0), "v"(h1));
        *(unsigned*)&h_lds[cur ^ 1][c*EE + ((w ^ c) << 3) + 2*q] = hp;

        if (IS_DEC){
            float p = h0*wl0 + h1*wl1;
            p += __shfl_xor(p, 16);
            if ((q & 1) == 0) psum_lds[cur][(2*w + (q >> 1))*16 + c] = p;
        }
        if (!IS_DEC && s == TT-1){
            *(float2*)&ws_h[gb*EE + e0] = make_float2(h0, h1);
            *(float2*)&ws_c[gb*EE + e0] = make_float2(cst0, cst1);
        }
        __syncthreads();
    }

    if (IS_DEC){
        if (w == 0 && lane < 16){   // flush last step (s=TT-1 -> position 0)
            float s32 = 0.f;
            #pragma unroll
            for (int j = 0; j < 32; ++j) s32 += psum_lds[(TT-1)&1][j*16 + lane];
            out_lds[lane][0] = s32 + bl_sh;
        }
        __syncthreads();
        for (int j = t; j < 16*TT; j += 1024){
            int sl = j >> 8, pos = j & 255;
            if (sl < nslots) out[blist[sl]*TT + pos] = out_lds[sl][pos];
        }
    }
}

extern "C" void kernel_launch(void* const* d_in, const int* in_sizes, int n_in,
                              void* d_out, int out_size, void* d_ws, size_t ws_size,
                              hipStream_t stream) {
    const float* x       = (const float*)d_in[0];
    const float* enc_wih = (const float*)d_in[1];
    const float* enc_whh = (const float*)d_in[2];
    const float* enc_b   = (const float*)d_in[3];
    const float* dec_wih = (const float*)d_in[4];
    const float* dec_whh = (const float*)d_in[5];
    const float* dec_b   = (const float*)d_in[6];
    const float* lin_w   = (const float*)d_in[7];
    const float* lin_b   = (const float*)d_in[8];
    float* out  = (float*)d_out;
    float* wsf  = (float*)d_ws;
    float* ws_h = wsf;
    float* ws_c = wsf + BB*EE;   // 512 KB total

    hipLaunchKernelGGL((lstm_k<0>), dim3(BB/16), dim3(1024), 0, stream,
                       x, enc_whh, enc_wih, enc_b, lin_w, lin_b, ws_h, ws_c, out);
    hipLaunchKernelGGL((lstm_k<1>), dim3(16*NCHUNK), dim3(1024), 0, stream,
                       x, dec_whh, dec_wih, dec_b, lin_w, lin_b, ws_h, ws_c, out);
}